// Round 5
// baseline (790.353 us; speedup 1.0000x reference)
//
#include <hip/hip_runtime.h>
#include <math.h>

#define IMG_H 1080
#define IMG_W 1920
#define NPIX (IMG_H * IMG_W)

#define TILE_H 8                 // row band height (pixels)
#define NROWS (IMG_H / TILE_H)   // 135 row bins
#define CHUNK_W 480              // shade x-chunk width
#define NCHUNK (IMG_W / CHUNK_W) // 4
#define BCAP 24                  // LDS slots per row bin in the bin pass
#define NBLK_BIN 512
#define CAP_MIN 73728            // required row capacity (hottest row ~67K)
#define CAP_MAX 131072

// Projection exactly mirroring the reference.
__device__ __forceinline__ void project_pt(
    const float* __restrict__ vm, const float* __restrict__ Km,
    float mx, float my, float mz,
    float& x, float& y, float& z, bool& on)
{
    float mcx = vm[0] * mx + vm[1] * my + vm[2]  * mz + vm[3];
    float mcy = vm[4] * mx + vm[5] * my + vm[6]  * mz + vm[7];
    float mcz = vm[8] * mx + vm[9] * my + vm[10] * mz + vm[11];
    z = mcz;
    bool front = z > 0.1f;
    float z_safe = front ? z : 1.0f;
    float fx = Km[0], fy = Km[4], cx = Km[2], cy = Km[5];
    x = mcx * fx / z_safe + cx;
    y = mcy * fy / z_safe + cy;
    on = front && (x >= 0.0f) && (x < (float)(IMG_W - 1))
               && (y >= 0.0f) && (y < (float)(IMG_H - 1));
}

// ===================== FAST PATH =====================
// Record (16B): x bits, y bits, z bits, rgb 10/10/10 (rgb is linear in the
// output; x,y,z exact fp32 — the w/(w+1e-6) cliff amplifies dx/dy error).
//
// k_binrow: stream gaussians once; stage records in LDS per-row buckets;
// flush full 16-record (256B-aligned) chunks with cooperative coalesced
// uint4 stores. Converts R3's 3.2M scattered-line RMWs (the measured
// ~10 G line/s ceiling) into ~219K full-line streaming bursts.

__global__ __launch_bounds__(256) void k_binrow(
    const float* __restrict__ means, const float* __restrict__ colors,
    const float* __restrict__ vm, const float* __restrict__ Km,
    unsigned int* __restrict__ gcur, uint4* __restrict__ rowrec,
    int cap, int N)
{
    __shared__ uint4 lbuf[NROWS * BCAP];          // 51,840 B
    __shared__ unsigned int lcnt[NROWS], lnf[NROWS], lbase[NROWS], lrem[NROWS];
    int tid = threadIdx.x;
    for (int r = tid; r < NROWS; r += 256) lcnt[r] = 0;
    __syncthreads();

    int per_block = ((N + NBLK_BIN - 1) / NBLK_BIN + 255) & ~255;
    int i0 = blockIdx.x * per_block;
    int iend = min(N, i0 + per_block);
    int rounds = (per_block + 255) / 256;

    for (int rd = 0; rd < rounds; ++rd) {
        // ---- append phase
        int i = i0 + rd * 256 + tid;
        bool emit = false, dup = false; int r0 = 0; uint4 rec;
        if (i < iend) {
            float x, y, z; bool on;
            project_pt(vm, Km, means[3 * i], means[3 * i + 1], means[3 * i + 2],
                       x, y, z, on);
            if (on) {
                float r = 1.0f / (1.0f + expf(-colors[3 * i]));
                float g = 1.0f / (1.0f + expf(-colors[3 * i + 1]));
                float b = 1.0f / (1.0f + expf(-colors[3 * i + 2]));
                unsigned int rq = (unsigned int)(r * 1023.0f + 0.5f);
                unsigned int gq = (unsigned int)(g * 1023.0f + 0.5f);
                unsigned int bq = (unsigned int)(b * 1023.0f + 0.5f);
                rec = make_uint4(__float_as_uint(x), __float_as_uint(y),
                                 __float_as_uint(z),
                                 (rq << 20) | (gq << 10) | bq);
                int y0 = (int)floorf(y);          // 0..1078
                r0 = y0 >> 3;
                dup = ((y0 & 7) == 7);            // corner row y0+1 in next band
                emit = true;
            }
        }
        if (emit) {
#pragma unroll
            for (int d = 0; d < 2; ++d) {
                if (d && !dup) break;
                int r = r0 + d;
                unsigned int slot = atomicAdd(&lcnt[r], 1u);
                if (slot < BCAP) {
                    lbuf[r * BCAP + slot] = rec;
                } else {            // rare overflow: direct scattered write
                    unsigned int gs = atomicAdd(&gcur[r], 1u);
                    if (gs < (unsigned int)cap)
                        rowrec[(size_t)r * cap + gs] = rec;
                }
            }
        }
        __syncthreads();
        // ---- flush decision (thread per bin)
        if (tid < NROWS) {
            unsigned int c = lcnt[tid]; if (c > BCAP) c = BCAP;
            unsigned int nf = (c >= 16u) ? 16u : 0u;
            lnf[tid] = nf;
            lrem[tid] = c - nf;
            if (nf) lbase[tid] = atomicAdd(&gcur[tid], nf);
        }
        __syncthreads();
        // ---- cooperative copy + compact (16 groups of 16 lanes)
        {
            int g = tid >> 4, lane = tid & 15;
            for (int r = g; r < NROWS; r += 16) {
                if (lnf[r]) {
                    unsigned int base = lbase[r];
                    if (base + lane < (unsigned int)cap)
                        rowrec[(size_t)r * cap + base + lane] =
                            lbuf[r * BCAP + lane];
                    unsigned int rem = lrem[r];          // <= 8
                    if (lane < rem)
                        lbuf[r * BCAP + lane] = lbuf[r * BCAP + 16 + lane];
                }
            }
        }
        __syncthreads();
        if (tid < NROWS) lcnt[tid] = lrem[tid];
        __syncthreads();
    }
    // ---- final ragged flush (remainder <= 15 per bin, contiguous)
    if (tid < NROWS) {
        unsigned int c = lcnt[tid]; if (c > BCAP) c = BCAP;   // c <= 15 here
        lnf[tid] = c;
        if (c) lbase[tid] = atomicAdd(&gcur[tid], c);
    }
    __syncthreads();
    {
        int g = tid >> 4, lane = tid & 15;
        for (int r = g; r < NROWS; r += 16) {
            unsigned int c = lnf[r];
            if (lane < c) {
                unsigned int base = lbase[r];
                if (base + lane < (unsigned int)cap)
                    rowrec[(size_t)r * cap + base + lane] = lbuf[r * BCAP + lane];
            }
        }
    }
}

// k_shade_strip: block = (tile-row, x-chunk) = 480x8 px. Scan the row bin
// twice (x-filtered): pass A builds per-pixel z-min with 1-px halo in LDS
// (complete: a gaussian touching pixel (y,x) has floor corner in
// [y-1,y]x[x-1,x], which is inside this row bin (y-dup) and the x-halo);
// pass B does the vis test + bilinear LDS accumulate; pass C normalizes and
// stores coalesced float4.
__global__ __launch_bounds__(256) void k_shade_strip(
    const unsigned int* __restrict__ gcur,
    const uint4* __restrict__ rowrec, int cap,
    float* __restrict__ out)
{
    __shared__ float acc[CHUNK_W * TILE_H * 5];                  // 76,800 B
    __shared__ unsigned int zm[(CHUNK_W + 1) * (TILE_H + 1)];    // 17,316 B
    int tid = threadIdx.x;
    int r  = blockIdx.x / NCHUNK;          // tile row
    int cc = blockIdx.x % NCHUNK;          // x chunk
    int cx0 = cc * CHUNK_W;
    int ry0 = r * TILE_H;

    for (int p = tid; p < (CHUNK_W + 1) * (TILE_H + 1); p += 256)
        zm[p] = 0x7F800000u;               // +inf bits (uint cmp == float, z>0)
    for (int p = tid; p < CHUNK_W * TILE_H * 5; p += 256) acc[p] = 0.0f;
    __syncthreads();

    int cnt = (int)min(gcur[r], (unsigned int)cap);
    const uint4* rec = rowrec + (size_t)r * cap;

    // Pass A: z-min (x-filtered)
    for (int j = tid; j < cnt; j += 256) {
        uint4 R = rec[j];
        float x = __uint_as_float(R.x);
        int lx = (int)floorf(x) - cx0;             // [-1, 479] relevant
        if ((unsigned)(lx + 1) > (unsigned)CHUNK_W) continue;
        float y = __uint_as_float(R.y);
        int sy = (int)floorf(y) - ry0;             // [-1, 7]
        atomicMin(&zm[(sy + 1) * (CHUNK_W + 1) + (lx + 1)], R.z);
    }
    __syncthreads();

    // Pass B: vis + accumulate
    for (int j = tid; j < cnt; j += 256) {
        uint4 R = rec[j];
        float x = __uint_as_float(R.x);
        float x0f = floorf(x);
        int lx = (int)x0f - cx0;
        if ((unsigned)(lx + 1) > (unsigned)CHUNK_W) continue;
        float y = __uint_as_float(R.y);
        float z = __uint_as_float(R.z);
        float y0f = floorf(y);
        int sy = (int)y0f - ry0;
        float zb = __uint_as_float(zm[(sy + 1) * (CHUNK_W + 1) + (lx + 1)]);
        if (!(z <= zb + 0.05f)) continue;
        float dx = x - x0f, dy = y - y0f;
        float wa = (1.0f - dx) * (1.0f - dy);
        float wb = dx * (1.0f - dy);
        float wc = (1.0f - dx) * dy;
        float wd = dx * dy;
        float cr = (float)((R.w >> 20) & 0x3FF) * (1.0f / 1023.0f);
        float cg = (float)((R.w >> 10) & 0x3FF) * (1.0f / 1023.0f);
        float cb = (float)(R.w & 0x3FF) * (1.0f / 1023.0f);
        // reference pairing: wa->(y0,x0) wb->(y1,x0) wc->(y0,x1) wd->(y1,x1)
        int cxs[4] = { lx, lx, lx + 1, lx + 1 };
        int cys[4] = { sy, sy + 1, sy, sy + 1 };
        float ws[4] = { wa, wb, wc, wd };
#pragma unroll
        for (int c = 0; c < 4; ++c) {
            int px = cxs[c], py = cys[c];
            if ((unsigned)px < CHUNK_W && (unsigned)py < TILE_H) {
                int bse = (py * CHUNK_W + px) * 5;
                float w = ws[c];
                atomicAdd(&acc[bse + 0], cr * w);
                atomicAdd(&acc[bse + 1], cg * w);
                atomicAdd(&acc[bse + 2], cb * w);
                atomicAdd(&acc[bse + 3], z * w);
                atomicAdd(&acc[bse + 4], w);
            }
        }
    }
    __syncthreads();

    // Pass C: normalize + coalesced store
    for (int p = tid; p < CHUNK_W * TILE_H; p += 256) {
        int bse = p * 5;
        float tot = acc[bse + 4] + 1e-6f;
        float rr = acc[bse + 0] / tot, gg = acc[bse + 1] / tot;
        float bb = acc[bse + 2] / tot, zz = acc[bse + 3] / tot;
        rr = fminf(fmaxf(rr, 0.0f), 1.0f);
        gg = fminf(fmaxf(gg, 0.0f), 1.0f);
        bb = fminf(fmaxf(bb, 0.0f), 1.0f);
        int py = p / CHUNK_W, px = p % CHUNK_W;
        reinterpret_cast<float4*>(out)[(ry0 + py) * IMG_W + cx0 + px] =
            make_float4(rr, gg, bb, zz);
    }
}

// ================= ROUND-1 FALLBACK (16.6 MB ws, proven) ====================

__global__ __launch_bounds__(256) void k_zmin(
    const float* __restrict__ means, const float* __restrict__ vm,
    const float* __restrict__ Km, unsigned int* __restrict__ zbuf, int N)
{
    int i = blockIdx.x * 256 + threadIdx.x;
    if (i >= N) return;
    float x, y, z; bool on;
    project_pt(vm, Km, means[3 * i], means[3 * i + 1], means[3 * i + 2], x, y, z, on);
    if (!on) return;
    int x0 = (int)floorf(x), y0 = (int)floorf(y);
    atomicMin(&zbuf[y0 * IMG_W + x0], __float_as_uint(z));
}

__global__ __launch_bounds__(256) void k_splat(
    const float* __restrict__ means, const float* __restrict__ colors,
    const float* __restrict__ vm, const float* __restrict__ Km,
    const float* __restrict__ zbuf,
    float* __restrict__ acc, float* __restrict__ wsum, int N)
{
    int i = blockIdx.x * 256 + threadIdx.x;
    if (i >= N) return;
    float x, y, z; bool on;
    project_pt(vm, Km, means[3 * i], means[3 * i + 1], means[3 * i + 2], x, y, z, on);
    if (!on) return;
    float x0f = floorf(x), y0f = floorf(y);
    int x0 = (int)x0f, y0 = (int)y0f;
    int pix = y0 * IMG_W + x0;
    if (!(z <= zbuf[pix] + 0.05f)) return;
    float dx = x - x0f, dy = y - y0f;
    float wa = (1.0f - dx) * (1.0f - dy);
    float wb = dx * (1.0f - dy);
    float wc = (1.0f - dx) * dy;
    float wd = dx * dy;
    float r = 1.0f / (1.0f + expf(-colors[3 * i]));
    float g = 1.0f / (1.0f + expf(-colors[3 * i + 1]));
    float b = 1.0f / (1.0f + expf(-colors[3 * i + 2]));
    int ia = pix, ib = pix + IMG_W, ic = pix + 1, id = pix + IMG_W + 1;
#define SPLAT1(idx, w)                                    \
    do {                                                  \
        atomicAdd(&acc[4 * (idx) + 0], r * (w));          \
        atomicAdd(&acc[4 * (idx) + 1], g * (w));          \
        atomicAdd(&acc[4 * (idx) + 2], b * (w));          \
        atomicAdd(&acc[4 * (idx) + 3], z * (w));          \
        atomicAdd(&wsum[(idx)], (w));                     \
    } while (0)
    SPLAT1(ia, wa); SPLAT1(ib, wb); SPLAT1(ic, wc); SPLAT1(id, wd);
#undef SPLAT1
}

__global__ __launch_bounds__(256) void k_final(
    float* __restrict__ out, const float* __restrict__ wsum)
{
    int p = blockIdx.x * 256 + threadIdx.x;
    if (p >= NPIX) return;
    float tot = wsum[p] + 1e-6f;
    float4 v = reinterpret_cast<float4*>(out)[p];
    float r = v.x / tot, g = v.y / tot, b = v.z / tot, zz = v.w / tot;
    r = fminf(fmaxf(r, 0.0f), 1.0f);
    g = fminf(fmaxf(g, 0.0f), 1.0f);
    b = fminf(fmaxf(b, 0.0f), 1.0f);
    reinterpret_cast<float4*>(out)[p] = make_float4(r, g, b, zz);
}

extern "C" void kernel_launch(void* const* d_in, const int* in_sizes, int n_in,
                              void* d_out, int out_size, void* d_ws, size_t ws_size,
                              hipStream_t stream)
{
    const float* means  = (const float*)d_in[0];
    const float* colors = (const float*)d_in[1];
    const float* vm     = (const float*)d_in[5];
    const float* Km     = (const float*)d_in[6];
    int N = in_sizes[0] / 3;
    float* out = (float*)d_out;

    const size_t recOff = 4096;   // row-cursor region (135 u32), 256B-aligned
    size_t cap_fit = ws_size > recOff
                   ? (ws_size - recOff) / ((size_t)NROWS * 16) : 0;
    long long cap = (long long)(cap_fit < CAP_MAX ? cap_fit : CAP_MAX);

    if (cap >= CAP_MIN) {
        unsigned int* gcur   = (unsigned int*)d_ws;
        uint4*        rowrec = (uint4*)((char*)d_ws + recOff);
        hipMemsetAsync(gcur, 0, recOff, stream);
        k_binrow<<<NBLK_BIN, 256, 0, stream>>>(means, colors, vm, Km,
                                               gcur, rowrec, (int)cap, N);
        k_shade_strip<<<NROWS * NCHUNK, 256, 0, stream>>>(
            (const unsigned int*)gcur, (const uint4*)rowrec, (int)cap, out);
    } else {
        const size_t zbufB = (size_t)NPIX * 4;
        unsigned int* zbuf = (unsigned int*)d_ws;
        float*        wsum = (float*)((char*)d_ws + zbufB);
        hipMemsetAsync(zbuf, 0x7f, zbufB, stream);
        hipMemsetAsync(wsum, 0x00, zbufB, stream);
        hipMemsetAsync(out,  0x00, (size_t)NPIX * 16, stream);
        int nb = (N + 255) / 256;
        k_zmin <<<nb, 256, 0, stream>>>(means, vm, Km, zbuf, N);
        k_splat<<<nb, 256, 0, stream>>>(means, colors, vm, Km,
                                        (const float*)zbuf, out, wsum, N);
        k_final<<<(NPIX + 255) / 256, 256, 0, stream>>>(out, wsum);
    }
}